// Round 1
// baseline (1466.326 us; speedup 1.0000x reference)
//
#include <hip/hip_runtime.h>
#include <cmath>

// Problem constants (from reference)
#define B_  2
#define H_  48
#define W_  48
#define DM  96
#define DE  192
#define K_  4
#define N_  16
#define R_  6
#define L_  (H_ * W_)          // 2304
#define CC  (R_ + 2 * N_)      // 38

__device__ __forceinline__ float silu_f(float x) { return x / (1.f + __expf(-x)); }
__device__ __forceinline__ float softplus_f(float x) {
    return x > 20.f ? x : log1pf(__expf(x));
}

// scan-position j -> original row-major spatial index, per direction k.
// Same map is used for the input gather and the output scatter (they coincide).
__device__ __forceinline__ int perm_idx(int k, int j) {
    if (k == 0) return j;
    if (k == 1) return L_ - 1 - j;
    if (k == 2) return (j % H_) * W_ + (j / H_);
    int m = L_ - 1 - j;
    return (m % H_) * W_ + (m / H_);
}

// ---------------------------------------------------------------------------
// K1: xz = x @ in_proj_w^T ; split -> xh (B,L,DE), z = silu (B,L,DE)
// one block per (b,l); 384 threads = one output channel each
// ---------------------------------------------------------------------------
__global__ void k_inproj(const float* __restrict__ x, const float* __restrict__ w,
                         float* __restrict__ xh, float* __restrict__ zb) {
    int bl = blockIdx.x;            // b*L + l
    int t  = threadIdx.x;           // 0..383
    __shared__ float xr[DM];
    if (t < DM) xr[t] = x[bl * DM + t];
    __syncthreads();
    const float* wr = w + t * DM;
    float acc = 0.f;
#pragma unroll
    for (int c = 0; c < DM; ++c) acc += xr[c] * wr[c];
    if (t < DE) xh[bl * DE + t] = acc;
    else        zb[bl * DE + (t - DE)] = silu_f(acc);
}

// ---------------------------------------------------------------------------
// K2: depthwise 3x3 SAME conv + bias + silu.  xh (B,L,DE) -> xc (B,L,DE)
// ---------------------------------------------------------------------------
__global__ void k_conv(const float* __restrict__ xh, const float* __restrict__ cw,
                       const float* __restrict__ cb, float* __restrict__ xc) {
    int t = blockIdx.x * blockDim.x + threadIdx.x;
    if (t >= B_ * L_ * DE) return;
    int d = t % DE;
    int l = (t / DE) % L_;
    int b = t / (DE * L_);
    int h = l / W_, w = l % W_;
    float acc = cb[d];
#pragma unroll
    for (int i = 0; i < 3; ++i) {
        int hh = h + i - 1;
        if (hh < 0 || hh >= H_) continue;
#pragma unroll
        for (int j = 0; j < 3; ++j) {
            int ww = w + j - 1;
            if (ww < 0 || ww >= W_) continue;
            acc += xh[((b * L_) + hh * W_ + ww) * DE + d] * cw[d * 9 + i * 3 + j];
        }
    }
    xc[t] = silu_f(acc);   // t == (b*L+l)*DE + d
}

// ---------------------------------------------------------------------------
// K3: per (b,k,j): x_dbl = x_proj_weight[k] @ xs[b,k,:,j]  (38 outputs)
//     -> Bs,Cs stored (B,K,L,N); dts (6) kept in LDS, immediately projected
//     through dt_projs_weight + bias + softplus -> delta (B,K,L,DE)
// ---------------------------------------------------------------------------
__global__ void k_proj(const float* __restrict__ xc, const float* __restrict__ xpw,
                       const float* __restrict__ dtw, const float* __restrict__ dtb,
                       float* __restrict__ BsT, float* __restrict__ CsT,
                       float* __restrict__ delta) {
    int bkj = blockIdx.x;           // (b*K+k)*L + j
    int j   = bkj % L_;
    int bk  = bkj / L_;
    int k   = bk % K_;
    int b   = bk / K_;
    int t   = threadIdx.x;          // 0..63
    int p   = perm_idx(k, j);

    __shared__ float xv[DE];
    __shared__ float pr[R_];
    const float* src = xc + (b * L_ + p) * DE;
    for (int i = t; i < DE; i += 64) xv[i] = src[i];
    __syncthreads();

    if (t < CC) {
        const float* wr = xpw + (k * CC + t) * DE;
        float acc = 0.f;
#pragma unroll 8
        for (int c = 0; c < DE; ++c) acc += xv[c] * wr[c];
        if (t < R_)            pr[t] = acc;
        else if (t < R_ + N_)  BsT[(bk * L_ + j) * N_ + (t - R_)] = acc;
        else                   CsT[(bk * L_ + j) * N_ + (t - R_ - N_)] = acc;
    }
    __syncthreads();

    for (int d = t; d < DE; d += 64) {
        const float* wr2 = dtw + (k * DE + d) * R_;
        float acc = dtb[k * DE + d];
#pragma unroll
        for (int r = 0; r < R_; ++r) acc += pr[r] * wr2[r];
        delta[(bk * L_ + j) * DE + d] = softplus_f(acc);
    }
}

// ---------------------------------------------------------------------------
// K4: selective scan. One 16-lane group per (b,k,d) chain; lane = state n.
//     h_n[j] = exp(delta*A_n)*h_n[j-1] + delta*u*B_n[j];
//     y[j]   = sum_n h_n[j]*C_n[j] + D*u  -> scattered to perm_k(j).
// ---------------------------------------------------------------------------
__global__ void k_scan(const float* __restrict__ xc, const float* __restrict__ BsT,
                       const float* __restrict__ CsT, const float* __restrict__ delta,
                       const float* __restrict__ A_logs, const float* __restrict__ Ds,
                       float* __restrict__ ysP) {
    int lane  = threadIdx.x;                 // 0..63
    int chain = blockIdx.x * 4 + (lane >> 4);
    int n     = lane & 15;
    int b = chain / (K_ * DE);
    int k = (chain / DE) % K_;
    int d = chain % DE;
    int bk = b * K_ + k;

    float An = -__expf(A_logs[(k * DE + d) * N_ + n]);
    float Dv = Ds[k * DE + d];

    const float* dptr = delta + bk * L_ * DE + d;
    const float* bptr = BsT + bk * L_ * N_ + n;
    const float* cptr = CsT + bk * L_ * N_ + n;
    const float* uptr = xc + b * L_ * DE + d;
    float*       yptr = ysP + bk * L_ * DE + d;

    float h = 0.f;
#pragma unroll 4
    for (int j = 0; j < L_; ++j) {
        int p = perm_idx(k, j);
        float dl = dptr[j * DE];
        float u  = uptr[p * DE];
        float Bv = bptr[j * N_];
        float Cv = cptr[j * N_];
        float e  = __expf(dl * An);
        h = e * h + dl * u * Bv;
        float part = h * Cv;
        part += __shfl_xor(part, 1, 16);
        part += __shfl_xor(part, 2, 16);
        part += __shfl_xor(part, 4, 16);
        part += __shfl_xor(part, 8, 16);
        if (n == 0) yptr[p * DE] = part + Dv * u;
    }
}

// ---------------------------------------------------------------------------
// K5: merge 4 directions + LayerNorm + *z + out-proj. One block per (b,l).
// ---------------------------------------------------------------------------
__global__ void k_out(const float* __restrict__ ysP, const float* __restrict__ zb,
                      const float* __restrict__ gamma, const float* __restrict__ beta,
                      const float* __restrict__ opw, float* __restrict__ out) {
    int bl = blockIdx.x;            // b*L + l
    int b  = bl / L_;
    int l  = bl % L_;
    int t  = threadIdx.x;           // 0..191
    __shared__ float ylds[DE];
    __shared__ float red[4];

    float v = 0.f;
#pragma unroll
    for (int k = 0; k < K_; ++k)
        v += ysP[((b * K_ + k) * L_ + l) * DE + t];

    float s = v;
    for (int off = 32; off; off >>= 1) s += __shfl_xor(s, off, 64);
    int wid = t >> 6, lane = t & 63;
    if (lane == 0) red[wid] = s;
    __syncthreads();
    float mu = (red[0] + red[1] + red[2]) * (1.f / DE);
    float tv = v - mu;
    float s2 = tv * tv;
    for (int off = 32; off; off >>= 1) s2 += __shfl_xor(s2, off, 64);
    __syncthreads();
    if (lane == 0) red[wid] = s2;
    __syncthreads();
    float var = (red[0] + red[1] + red[2]) * (1.f / DE);

    float yn = tv * rsqrtf(var + 1e-5f) * gamma[t] + beta[t];
    ylds[t] = yn * zb[bl * DE + t];
    __syncthreads();

    if (t < DM) {
        const float* wr = opw + t * DE;
        float acc = 0.f;
#pragma unroll 8
        for (int d = 0; d < DE; ++d) acc += ylds[d] * wr[d];
        out[bl * DM + t] = acc;
    }
}

// ---------------------------------------------------------------------------
extern "C" void kernel_launch(void* const* d_in, const int* in_sizes, int n_in,
                              void* d_out, int out_size, void* d_ws, size_t ws_size,
                              hipStream_t stream) {
    const float* x    = (const float*)d_in[0];
    const float* wip  = (const float*)d_in[1];
    const float* cw   = (const float*)d_in[2];
    const float* cb   = (const float*)d_in[3];
    const float* xpw  = (const float*)d_in[4];
    const float* dtw  = (const float*)d_in[5];
    const float* dtb  = (const float*)d_in[6];
    const float* alog = (const float*)d_in[7];
    const float* Ds   = (const float*)d_in[8];
    const float* gam  = (const float*)d_in[9];
    const float* bet  = (const float*)d_in[10];
    const float* opw  = (const float*)d_in[11];
    float* out = (float*)d_out;

    float* ws    = (float*)d_ws;
    float* xh    = ws;                       // B*L*DE = 884736
    float* zb    = xh + B_ * L_ * DE;        // 884736
    float* xc    = zb + B_ * L_ * DE;        // 884736
    float* BsT   = xc + B_ * L_ * DE;        // B*K*L*N = 294912
    float* CsT   = BsT + B_ * K_ * L_ * N_;  // 294912
    float* delta = CsT + B_ * K_ * L_ * N_;  // B*K*L*DE = 3538944
    float* ysP   = delta + B_ * K_ * L_ * DE;// 3538944
    // total ~41.3 MB of d_ws

    k_inproj<<<B_ * L_, 2 * DE, 0, stream>>>(x, wip, xh, zb);
    k_conv<<<(B_ * L_ * DE + 255) / 256, 256, 0, stream>>>(xh, cw, cb, xc);
    k_proj<<<B_ * K_ * L_, 64, 0, stream>>>(xc, xpw, dtw, dtb, BsT, CsT, delta);
    k_scan<<<(B_ * K_ * DE) / 4, 64, 0, stream>>>(xc, BsT, CsT, delta, alog, Ds, ysP);
    k_out<<<B_ * L_, DE, 0, stream>>>(ysP, zb, gam, bet, opw, out);
}

// Round 2
// 493.406 us; speedup vs baseline: 2.9718x; 2.9718x over previous
//
#include <hip/hip_runtime.h>
#include <cmath>

// Problem constants (from reference)
#define B_  2
#define H_  48
#define W_  48
#define DM  96
#define DE  192
#define K_  4
#define N_  16
#define R_  6
#define L_  (H_ * W_)          // 2304
#define CC  (R_ + 2 * N_)      // 38
#define CH_ 24                 // chunks per chain (one workgroup = one chain)
#define LC_ (L_ / CH_)         // 96 steps per chunk

__device__ __forceinline__ float silu_f(float x) { return x / (1.f + __expf(-x)); }
__device__ __forceinline__ float softplus_f(float x) {
    return x > 20.f ? x : log1pf(__expf(x));
}

// scan-position j -> original row-major spatial index, per direction k.
// Same map is used for the input gather and the output scatter (they coincide).
__device__ __forceinline__ int perm_idx(int k, int j) {
    if (k == 0) return j;
    if (k == 1) return L_ - 1 - j;
    if (k == 2) return (j % H_) * W_ + (j / H_);
    int m = L_ - 1 - j;
    return (m % H_) * W_ + (m / H_);
}

// ---------------------------------------------------------------------------
// K1: xz = x @ in_proj_w^T ; split -> xh (B,L,DE), z = silu (B,L,DE)
// ---------------------------------------------------------------------------
__global__ void k_inproj(const float* __restrict__ x, const float* __restrict__ w,
                         float* __restrict__ xh, float* __restrict__ zb) {
    int bl = blockIdx.x;            // b*L + l
    int t  = threadIdx.x;           // 0..383
    __shared__ float xr[DM];
    if (t < DM) xr[t] = x[bl * DM + t];
    __syncthreads();
    const float* wr = w + t * DM;
    float acc = 0.f;
#pragma unroll
    for (int c = 0; c < DM; ++c) acc += xr[c] * wr[c];
    if (t < DE) xh[bl * DE + t] = acc;
    else        zb[bl * DE + (t - DE)] = silu_f(acc);
}

// ---------------------------------------------------------------------------
// K2: depthwise 3x3 SAME conv + bias + silu.  xh (B,L,DE) -> xc (B,L,DE)
// ---------------------------------------------------------------------------
__global__ void k_conv(const float* __restrict__ xh, const float* __restrict__ cw,
                       const float* __restrict__ cb, float* __restrict__ xc) {
    int t = blockIdx.x * blockDim.x + threadIdx.x;
    if (t >= B_ * L_ * DE) return;
    int d = t % DE;
    int l = (t / DE) % L_;
    int b = t / (DE * L_);
    int h = l / W_, w = l % W_;
    float acc = cb[d];
#pragma unroll
    for (int i = 0; i < 3; ++i) {
        int hh = h + i - 1;
        if (hh < 0 || hh >= H_) continue;
#pragma unroll
        for (int j = 0; j < 3; ++j) {
            int ww = w + j - 1;
            if (ww < 0 || ww >= W_) continue;
            acc += xh[((b * L_) + hh * W_ + ww) * DE + d] * cw[d * 9 + i * 3 + j];
        }
    }
    xc[t] = silu_f(acc);   // t == (b*L+l)*DE + d
}

// ---------------------------------------------------------------------------
// K3: per (b,k,j): x_dbl = x_proj_weight[k] @ xs[b,k,:,j]  (38 outputs)
//     -> Bs,Cs stored (B,K,L,N); dts (6) kept in LDS, immediately projected
//     through dt_projs_weight + bias + softplus -> delta (B,K,L,DE)
// ---------------------------------------------------------------------------
__global__ void k_proj(const float* __restrict__ xc, const float* __restrict__ xpw,
                       const float* __restrict__ dtw, const float* __restrict__ dtb,
                       float* __restrict__ BsT, float* __restrict__ CsT,
                       float* __restrict__ delta) {
    int bkj = blockIdx.x;           // (b*K+k)*L + j
    int j   = bkj % L_;
    int bk  = bkj / L_;
    int k   = bk % K_;
    int b   = bk / K_;
    int t   = threadIdx.x;          // 0..63
    int p   = perm_idx(k, j);

    __shared__ float xv[DE];
    __shared__ float pr[R_];
    const float* src = xc + (b * L_ + p) * DE;
    for (int i = t; i < DE; i += 64) xv[i] = src[i];
    __syncthreads();

    if (t < CC) {
        const float* wr = xpw + (k * CC + t) * DE;
        float acc = 0.f;
#pragma unroll 8
        for (int c = 0; c < DE; ++c) acc += xv[c] * wr[c];
        if (t < R_)            pr[t] = acc;
        else if (t < R_ + N_)  BsT[(bk * L_ + j) * N_ + (t - R_)] = acc;
        else                   CsT[(bk * L_ + j) * N_ + (t - R_ - N_)] = acc;
    }
    __syncthreads();

    for (int d = t; d < DE; d += 64) {
        const float* wr2 = dtw + (k * DE + d) * R_;
        float acc = dtb[k * DE + d];
#pragma unroll
        for (int r = 0; r < R_; ++r) acc += pr[r] * wr2[r];
        delta[(bk * L_ + j) * DE + d] = softplus_f(acc);
    }
}

// ---------------------------------------------------------------------------
// K4: chunked selective scan. One workgroup per (b,k,d) chain.
//     384 threads = 24 chunks x 16 states. Phase 1: local chunk scan
//     (affine summary E=prod e, h_end). Phase 2: LDS sequential combine
//     over 24 chunks. Phase 3: rescan with carry, emit y (shuffle-reduced
//     over the 16 states), scattered to perm_k(j).
// ---------------------------------------------------------------------------
__global__ __launch_bounds__(CH_ * N_) void
k_scan(const float* __restrict__ xc, const float* __restrict__ BsT,
       const float* __restrict__ CsT, const float* __restrict__ delta,
       const float* __restrict__ A_logs, const float* __restrict__ Ds,
       float* __restrict__ ysP) {
    int chain = blockIdx.x;                  // 0..B*K*DE-1
    int t     = threadIdx.x;                 // 0..383
    int chunk = t >> 4;                      // 0..23
    int n     = t & 15;                      // state index
    int b = chain / (K_ * DE);
    int k = (chain / DE) % K_;
    int d = chain % DE;
    int bk = b * K_ + k;

    float An = -__expf(A_logs[(k * DE + d) * N_ + n]);
    float Dv = Ds[k * DE + d];

    const float* dptr = delta + (size_t)bk * L_ * DE + d;
    const float* bptr = BsT + (size_t)bk * L_ * N_ + n;
    const float* cptr = CsT + (size_t)bk * L_ * N_ + n;
    const float* uptr = xc + (size_t)b * L_ * DE + d;
    float*       yptr = ysP + (size_t)bk * L_ * DE + d;

    __shared__ float Es[CH_][N_];
    __shared__ float Hs[CH_][N_];
    __shared__ float Cin[CH_][N_];

    const int j0 = chunk * LC_;

    // ---- phase 1: local scan from h=0, accumulate chunk transition ----
    float E = 1.f, h = 0.f;
#pragma unroll 8
    for (int jj = 0; jj < LC_; ++jj) {
        int j = j0 + jj;
        int p = perm_idx(k, j);
        float dl = dptr[(size_t)j * DE];
        float u  = uptr[(size_t)p * DE];
        float Bv = bptr[(size_t)j * N_];
        float e  = __expf(dl * An);
        E *= e;
        h = e * h + dl * u * Bv;
    }
    Es[chunk][n] = E;
    Hs[chunk][n] = h;
    __syncthreads();

    // ---- phase 2: sequential combine of 24 chunk summaries (16 lanes) ----
    if (t < N_) {
        float carry = 0.f;
#pragma unroll
        for (int c = 0; c < CH_; ++c) {
            Cin[c][t] = carry;
            carry = Es[c][t] * carry + Hs[c][t];
        }
    }
    __syncthreads();

    // ---- phase 3: rescan with true carry, emit y ----
    h = Cin[chunk][n];
#pragma unroll 4
    for (int jj = 0; jj < LC_; ++jj) {
        int j = j0 + jj;
        int p = perm_idx(k, j);
        float dl = dptr[(size_t)j * DE];
        float u  = uptr[(size_t)p * DE];
        float Bv = bptr[(size_t)j * N_];
        float Cv = cptr[(size_t)j * N_];
        float e  = __expf(dl * An);
        h = e * h + dl * u * Bv;
        float part = h * Cv;
        part += __shfl_xor(part, 1, 16);
        part += __shfl_xor(part, 2, 16);
        part += __shfl_xor(part, 4, 16);
        part += __shfl_xor(part, 8, 16);
        if (n == 0) yptr[(size_t)p * DE] = part + Dv * u;
    }
}

// ---------------------------------------------------------------------------
// K5: merge 4 directions + LayerNorm + *z + out-proj. One block per (b,l).
// ---------------------------------------------------------------------------
__global__ void k_out(const float* __restrict__ ysP, const float* __restrict__ zb,
                      const float* __restrict__ gamma, const float* __restrict__ beta,
                      const float* __restrict__ opw, float* __restrict__ out) {
    int bl = blockIdx.x;            // b*L + l
    int b  = bl / L_;
    int l  = bl % L_;
    int t  = threadIdx.x;           // 0..191
    __shared__ float ylds[DE];
    __shared__ float red[4];

    float v = 0.f;
#pragma unroll
    for (int k = 0; k < K_; ++k)
        v += ysP[((b * K_ + k) * L_ + l) * DE + t];

    float s = v;
    for (int off = 32; off; off >>= 1) s += __shfl_xor(s, off, 64);
    int wid = t >> 6, lane = t & 63;
    if (lane == 0) red[wid] = s;
    __syncthreads();
    float mu = (red[0] + red[1] + red[2]) * (1.f / DE);
    float tv = v - mu;
    float s2 = tv * tv;
    for (int off = 32; off; off >>= 1) s2 += __shfl_xor(s2, off, 64);
    __syncthreads();
    if (lane == 0) red[wid] = s2;
    __syncthreads();
    float var = (red[0] + red[1] + red[2]) * (1.f / DE);

    float yn = tv * rsqrtf(var + 1e-5f) * gamma[t] + beta[t];
    ylds[t] = yn * zb[bl * DE + t];
    __syncthreads();

    if (t < DM) {
        const float* wr = opw + t * DE;
        float acc = 0.f;
#pragma unroll 8
        for (int d = 0; d < DE; ++d) acc += ylds[d] * wr[d];
        out[bl * DM + t] = acc;
    }
}

// ---------------------------------------------------------------------------
extern "C" void kernel_launch(void* const* d_in, const int* in_sizes, int n_in,
                              void* d_out, int out_size, void* d_ws, size_t ws_size,
                              hipStream_t stream) {
    const float* x    = (const float*)d_in[0];
    const float* wip  = (const float*)d_in[1];
    const float* cw   = (const float*)d_in[2];
    const float* cb   = (const float*)d_in[3];
    const float* xpw  = (const float*)d_in[4];
    const float* dtw  = (const float*)d_in[5];
    const float* dtb  = (const float*)d_in[6];
    const float* alog = (const float*)d_in[7];
    const float* Ds   = (const float*)d_in[8];
    const float* gam  = (const float*)d_in[9];
    const float* bet  = (const float*)d_in[10];
    const float* opw  = (const float*)d_in[11];
    float* out = (float*)d_out;

    float* ws    = (float*)d_ws;
    float* xh    = ws;                       // B*L*DE = 884736
    float* zb    = xh + B_ * L_ * DE;        // 884736
    float* xc    = zb + B_ * L_ * DE;        // 884736
    float* BsT   = xc + B_ * L_ * DE;        // B*K*L*N = 294912
    float* CsT   = BsT + B_ * K_ * L_ * N_;  // 294912
    float* delta = CsT + B_ * K_ * L_ * N_;  // B*K*L*DE = 3538944
    float* ysP   = delta + B_ * K_ * L_ * DE;// 3538944
    // total ~41.3 MB of d_ws

    k_inproj<<<B_ * L_, 2 * DE, 0, stream>>>(x, wip, xh, zb);
    k_conv<<<(B_ * L_ * DE + 255) / 256, 256, 0, stream>>>(xh, cw, cb, xc);
    k_proj<<<B_ * K_ * L_, 64, 0, stream>>>(xc, xpw, dtw, dtb, BsT, CsT, delta);
    k_scan<<<B_ * K_ * DE, CH_ * N_, 0, stream>>>(xc, BsT, CsT, delta, alog, Ds, ysP);
    k_out<<<B_ * L_, DE, 0, stream>>>(ysP, zb, gam, bet, opw, out);
}

// Round 3
// 366.592 us; speedup vs baseline: 3.9999x; 1.3459x over previous
//
#include <hip/hip_runtime.h>
#include <cmath>

// Problem constants (from reference)
#define B_  2
#define H_  48
#define W_  48
#define DM  96
#define DE  192
#define K_  4
#define N_  16
#define R_  6
#define L_  (H_ * W_)          // 2304
#define CC  (R_ + 2 * N_)      // 38
#define CH_ 96                 // chunks per (b,k) chain-group
#define LC_ (L_ / CH_)         // 24 steps per chunk
#define JT_ 16                 // j-tile in k_proj

__device__ __forceinline__ float silu_f(float x) { return x / (1.f + __expf(-x)); }
__device__ __forceinline__ float softplus_f(float x) {
    return x > 20.f ? x : log1pf(__expf(x));
}

// scan-position j -> original row-major spatial index, per direction k.
__device__ __forceinline__ int perm_idx(int k, int j) {
    if (k == 0) return j;
    if (k == 1) return L_ - 1 - j;
    if (k == 2) return (j % H_) * W_ + (j / H_);
    int m = L_ - 1 - j;
    return (m % H_) * W_ + (m / H_);
}

// ---------------------------------------------------------------------------
// K1: xz = x @ in_proj_w^T ; split -> xh (B,L,DE), z = silu (B,L,DE)
// ---------------------------------------------------------------------------
__global__ void k_inproj(const float* __restrict__ x, const float* __restrict__ w,
                         float* __restrict__ xh, float* __restrict__ zb) {
    int bl = blockIdx.x;            // b*L + l
    int t  = threadIdx.x;           // 0..383
    __shared__ __align__(16) float xr[DM];
    if (t < DM) xr[t] = x[bl * DM + t];
    __syncthreads();
    const float4* wr4 = (const float4*)(w + t * DM);
    const float4* xr4 = (const float4*)xr;
    float acc = 0.f;
#pragma unroll
    for (int c = 0; c < DM / 4; ++c) {
        float4 a = xr4[c], b = wr4[c];
        acc += a.x * b.x + a.y * b.y + a.z * b.z + a.w * b.w;
    }
    if (t < DE) xh[bl * DE + t] = acc;
    else        zb[bl * DE + (t - DE)] = silu_f(acc);
}

// ---------------------------------------------------------------------------
// K2: depthwise 3x3 SAME conv + bias + silu.  xh (B,L,DE) -> xc (B,L,DE)
// ---------------------------------------------------------------------------
__global__ void k_conv(const float* __restrict__ xh, const float* __restrict__ cw,
                       const float* __restrict__ cb, float* __restrict__ xc) {
    int t = blockIdx.x * blockDim.x + threadIdx.x;
    if (t >= B_ * L_ * DE) return;
    int d = t % DE;
    int l = (t / DE) % L_;
    int b = t / (DE * L_);
    int h = l / W_, w = l % W_;
    float acc = cb[d];
#pragma unroll
    for (int i = 0; i < 3; ++i) {
        int hh = h + i - 1;
        if (hh < 0 || hh >= H_) continue;
#pragma unroll
        for (int j = 0; j < 3; ++j) {
            int ww = w + j - 1;
            if (ww < 0 || ww >= W_) continue;
            acc += xh[((b * L_) + hh * W_ + ww) * DE + d] * cw[d * 9 + i * 3 + j];
        }
    }
    xc[t] = silu_f(acc);
}

// ---------------------------------------------------------------------------
// K3: j-tiled projection. Block = (bk, tile of 16 j). Computes the 38-row
//     x_proj for 16 positions; writes Bs,Cs (B,K,L,N) and dts (B,K,L,R).
//     delta is NOT materialized (recomputed in-scan from dts).
// ---------------------------------------------------------------------------
__global__ __launch_bounds__(256) void
k_proj(const float* __restrict__ xc, const float* __restrict__ xpw,
       float* __restrict__ BsT, float* __restrict__ CsT, float* __restrict__ dts) {
    int blk = blockIdx.x;                // bk * (L/JT) + tile
    int jt  = blk % (L_ / JT_);
    int bk  = blk / (L_ / JT_);
    int k   = bk % K_;
    int b   = bk / K_;
    int j0  = jt * JT_;
    int t   = threadIdx.x;

    __shared__ __align__(16) float xv[JT_][DE];   // 12 KB
    for (int idx = t; idx < JT_ * DE; idx += 256) {
        int jj = idx / DE, dd = idx % DE;
        int p  = perm_idx(k, j0 + jj);
        xv[jj][dd] = xc[((size_t)b * L_ + p) * DE + dd];
    }
    __syncthreads();

    for (int o = t; o < JT_ * CC; o += 256) {
        int jj = o / CC, c = o % CC;
        const float4* wr4 = (const float4*)(xpw + ((size_t)k * CC + c) * DE);
        const float4* xv4 = (const float4*)xv[jj];
        float acc = 0.f;
#pragma unroll 12
        for (int i = 0; i < DE / 4; ++i) {
            float4 a = xv4[i], wv = wr4[i];
            acc += a.x * wv.x + a.y * wv.y + a.z * wv.z + a.w * wv.w;
        }
        int j = j0 + jj;
        if (c < R_)            dts[((size_t)bk * L_ + j) * R_ + c] = acc;
        else if (c < R_ + N_)  BsT[((size_t)bk * L_ + j) * N_ + (c - R_)] = acc;
        else                   CsT[((size_t)bk * L_ + j) * N_ + (c - R_ - N_)] = acc;
    }
}

// ---------------------------------------------------------------------------
// K4a: chunk-local scan. Block = (bk, chunk); thread = channel d, holding all
//      16 n-states in registers. All global accesses coalesced 768B rows.
//      Emits h_end (Hsum) and sum of delta (dlsum) per chunk.
// ---------------------------------------------------------------------------
__global__ __launch_bounds__(DE) void
k_scan1(const float* __restrict__ xc, const float* __restrict__ BsT,
        const float* __restrict__ dts, const float* __restrict__ dtw,
        const float* __restrict__ dtb, const float* __restrict__ A_logs,
        float* __restrict__ Hsum, float* __restrict__ dlsum_g) {
    int blk = blockIdx.x;            // bk*CH_ + c
    int c   = blk % CH_;
    int bk  = blk / CH_;
    int k   = bk % K_;
    int b   = bk / K_;
    int d   = threadIdx.x;           // 0..191
    int j0  = c * LC_;

    __shared__ __align__(16) float Bl[LC_ * N_];
    __shared__ __align__(16) float Tl[LC_ * R_];
    for (int idx = d; idx < LC_ * N_; idx += DE)
        Bl[idx] = BsT[((size_t)bk * L_ + j0) * N_ + idx];
    for (int idx = d; idx < LC_ * R_; idx += DE)
        Tl[idx] = dts[((size_t)bk * L_ + j0) * R_ + idx];
    __syncthreads();

    float An[N_];
    {
        const float4* Ap = (const float4*)(A_logs + ((size_t)k * DE + d) * N_);
#pragma unroll
        for (int q = 0; q < 4; ++q) {
            float4 a = Ap[q];
            An[4*q+0] = -__expf(a.x); An[4*q+1] = -__expf(a.y);
            An[4*q+2] = -__expf(a.z); An[4*q+3] = -__expf(a.w);
        }
    }
    float wdt[R_];
#pragma unroll
    for (int r = 0; r < R_; ++r) wdt[r] = dtw[((size_t)k * DE + d) * R_ + r];
    float bias = dtb[k * DE + d];

    float h[N_];
#pragma unroll
    for (int n = 0; n < N_; ++n) h[n] = 0.f;
    float dlsum = 0.f;

    const float* up = xc + (size_t)b * L_ * DE + d;
#pragma unroll 4
    for (int jj = 0; jj < LC_; ++jj) {
        int j = j0 + jj;
        int p = perm_idx(k, j);
        float u  = up[(size_t)p * DE];
        float dt = bias;
#pragma unroll
        for (int r = 0; r < R_; ++r) dt += Tl[jj * R_ + r] * wdt[r];
        float dl = softplus_f(dt);
        dlsum += dl;
        float du = dl * u;
        const float4* B4 = (const float4*)(Bl + jj * N_);
#pragma unroll
        for (int q = 0; q < 4; ++q) {
            float4 bq = B4[q];
            h[4*q+0] = __expf(dl * An[4*q+0]) * h[4*q+0] + du * bq.x;
            h[4*q+1] = __expf(dl * An[4*q+1]) * h[4*q+1] + du * bq.y;
            h[4*q+2] = __expf(dl * An[4*q+2]) * h[4*q+2] + du * bq.z;
            h[4*q+3] = __expf(dl * An[4*q+3]) * h[4*q+3] + du * bq.w;
        }
    }
    float4* Hp = (float4*)Hsum;
#pragma unroll
    for (int q = 0; q < 4; ++q)
        Hp[((size_t)blk * 4 + q) * DE + d] =
            make_float4(h[4*q], h[4*q+1], h[4*q+2], h[4*q+3]);
    dlsum_g[(size_t)blk * DE + d] = dlsum;
}

// ---------------------------------------------------------------------------
// K4b: sequential combine of chunk summaries -> carry_in per chunk.
//      thread = (bk, q, d) handling 4 n-states as float4.
// ---------------------------------------------------------------------------
__global__ __launch_bounds__(256) void
k_comb(const float* __restrict__ Hsum, const float* __restrict__ dlsum_g,
       const float* __restrict__ A_logs, float* __restrict__ carry) {
    int tid = blockIdx.x * 256 + threadIdx.x;  // d fastest
    int d  = tid % DE;
    int q  = (tid / DE) % 4;
    int bk = tid / (DE * 4);
    int k  = bk % K_;
    float4 An;
    {
        const float4* Ap = (const float4*)(A_logs + ((size_t)k * DE + d) * N_);
        float4 a = Ap[q];
        An = make_float4(-__expf(a.x), -__expf(a.y), -__expf(a.z), -__expf(a.w));
    }
    const float4* Hp = (const float4*)Hsum;
    float4*       Cp = (float4*)carry;
    float4 cy = make_float4(0.f, 0.f, 0.f, 0.f);
#pragma unroll 4
    for (int c = 0; c < CH_; ++c) {
        size_t blk = (size_t)bk * CH_ + c;
        Cp[(blk * 4 + q) * DE + d] = cy;
        float  ds = dlsum_g[blk * DE + d];
        float4 H  = Hp[(blk * 4 + q) * DE + d];
        cy.x = __expf(ds * An.x) * cy.x + H.x;
        cy.y = __expf(ds * An.y) * cy.y + H.y;
        cy.z = __expf(ds * An.z) * cy.z + H.z;
        cy.w = __expf(ds * An.w) * cy.w + H.w;
    }
}

// ---------------------------------------------------------------------------
// K4c: rescan with carry, emit y via atomicAdd into yacc (B,L,DE).
// ---------------------------------------------------------------------------
__global__ __launch_bounds__(DE) void
k_scan2(const float* __restrict__ xc, const float* __restrict__ BsT,
        const float* __restrict__ CsT, const float* __restrict__ dts,
        const float* __restrict__ dtw, const float* __restrict__ dtb,
        const float* __restrict__ A_logs, const float* __restrict__ Ds,
        const float* __restrict__ carry, float* __restrict__ yacc) {
    int blk = blockIdx.x;
    int c   = blk % CH_;
    int bk  = blk / CH_;
    int k   = bk % K_;
    int b   = bk / K_;
    int d   = threadIdx.x;
    int j0  = c * LC_;

    __shared__ __align__(16) float Bl[LC_ * N_];
    __shared__ __align__(16) float Cl[LC_ * N_];
    __shared__ __align__(16) float Tl[LC_ * R_];
    for (int idx = d; idx < LC_ * N_; idx += DE) {
        Bl[idx] = BsT[((size_t)bk * L_ + j0) * N_ + idx];
        Cl[idx] = CsT[((size_t)bk * L_ + j0) * N_ + idx];
    }
    for (int idx = d; idx < LC_ * R_; idx += DE)
        Tl[idx] = dts[((size_t)bk * L_ + j0) * R_ + idx];
    __syncthreads();

    float An[N_];
    {
        const float4* Ap = (const float4*)(A_logs + ((size_t)k * DE + d) * N_);
#pragma unroll
        for (int q = 0; q < 4; ++q) {
            float4 a = Ap[q];
            An[4*q+0] = -__expf(a.x); An[4*q+1] = -__expf(a.y);
            An[4*q+2] = -__expf(a.z); An[4*q+3] = -__expf(a.w);
        }
    }
    float wdt[R_];
#pragma unroll
    for (int r = 0; r < R_; ++r) wdt[r] = dtw[((size_t)k * DE + d) * R_ + r];
    float bias = dtb[k * DE + d];
    float Dv   = Ds[k * DE + d];

    float h[N_];
    {
        const float4* Cp = (const float4*)carry;
#pragma unroll
        for (int q = 0; q < 4; ++q) {
            float4 cv = Cp[((size_t)blk * 4 + q) * DE + d];
            h[4*q+0] = cv.x; h[4*q+1] = cv.y; h[4*q+2] = cv.z; h[4*q+3] = cv.w;
        }
    }

    const float* up = xc + (size_t)b * L_ * DE + d;
    float*       yp = yacc + (size_t)b * L_ * DE + d;
#pragma unroll 2
    for (int jj = 0; jj < LC_; ++jj) {
        int j = j0 + jj;
        int p = perm_idx(k, j);
        float u  = up[(size_t)p * DE];
        float dt = bias;
#pragma unroll
        for (int r = 0; r < R_; ++r) dt += Tl[jj * R_ + r] * wdt[r];
        float dl = softplus_f(dt);
        float du = dl * u;
        float y  = Dv * u;
        const float4* B4 = (const float4*)(Bl + jj * N_);
        const float4* C4 = (const float4*)(Cl + jj * N_);
#pragma unroll
        for (int q = 0; q < 4; ++q) {
            float4 bq = B4[q], cq = C4[q];
            h[4*q+0] = __expf(dl * An[4*q+0]) * h[4*q+0] + du * bq.x;  y += h[4*q+0] * cq.x;
            h[4*q+1] = __expf(dl * An[4*q+1]) * h[4*q+1] + du * bq.y;  y += h[4*q+1] * cq.y;
            h[4*q+2] = __expf(dl * An[4*q+2]) * h[4*q+2] + du * bq.z;  y += h[4*q+2] * cq.z;
            h[4*q+3] = __expf(dl * An[4*q+3]) * h[4*q+3] + du * bq.w;  y += h[4*q+3] * cq.w;
        }
        atomicAdd(&yp[(size_t)p * DE], y);
    }
}

// ---------------------------------------------------------------------------
// K5: LayerNorm + *z + out-proj. One block per (b,l). yacc already merged.
// ---------------------------------------------------------------------------
__global__ void k_out(const float* __restrict__ yacc, const float* __restrict__ zb,
                      const float* __restrict__ gamma, const float* __restrict__ beta,
                      const float* __restrict__ opw, float* __restrict__ out) {
    int bl = blockIdx.x;            // b*L + l
    int t  = threadIdx.x;           // 0..191
    __shared__ __align__(16) float ylds[DE];
    __shared__ float red[4];

    float v = yacc[(size_t)bl * DE + t];

    float s = v;
    for (int off = 32; off; off >>= 1) s += __shfl_xor(s, off, 64);
    int wid = t >> 6, lane = t & 63;
    if (lane == 0) red[wid] = s;
    __syncthreads();
    float mu = (red[0] + red[1] + red[2]) * (1.f / DE);
    float tv = v - mu;
    float s2 = tv * tv;
    for (int off = 32; off; off >>= 1) s2 += __shfl_xor(s2, off, 64);
    __syncthreads();
    if (lane == 0) red[wid] = s2;
    __syncthreads();
    float var = (red[0] + red[1] + red[2]) * (1.f / DE);

    float yn = tv * rsqrtf(var + 1e-5f) * gamma[t] + beta[t];
    ylds[t] = yn * zb[(size_t)bl * DE + t];
    __syncthreads();

    if (t < DM) {
        const float4* wr4 = (const float4*)(opw + t * DE);
        const float4* y4  = (const float4*)ylds;
        float acc = 0.f;
#pragma unroll 12
        for (int i = 0; i < DE / 4; ++i) {
            float4 a = y4[i], wv = wr4[i];
            acc += a.x * wv.x + a.y * wv.y + a.z * wv.z + a.w * wv.w;
        }
        out[(size_t)bl * DM + t] = acc;
    }
}

// ---------------------------------------------------------------------------
extern "C" void kernel_launch(void* const* d_in, const int* in_sizes, int n_in,
                              void* d_out, int out_size, void* d_ws, size_t ws_size,
                              hipStream_t stream) {
    const float* x    = (const float*)d_in[0];
    const float* wip  = (const float*)d_in[1];
    const float* cw   = (const float*)d_in[2];
    const float* cb   = (const float*)d_in[3];
    const float* xpw  = (const float*)d_in[4];
    const float* dtw  = (const float*)d_in[5];
    const float* dtb  = (const float*)d_in[6];
    const float* alog = (const float*)d_in[7];
    const float* Ds   = (const float*)d_in[8];
    const float* gam  = (const float*)d_in[9];
    const float* bet  = (const float*)d_in[10];
    const float* opw  = (const float*)d_in[11];
    float* out = (float*)d_out;

    float* ws    = (float*)d_ws;
    float* xh    = ws;                        // B*L*DE   =  884736
    float* zb    = xh   + 884736;             //             884736
    float* xc    = zb   + 884736;             //             884736
    float* BsT   = xc   + 884736;             // B*K*L*N  =  294912
    float* CsT   = BsT  + 294912;             //             294912
    float* dts   = CsT  + 294912;             // B*K*L*R  =  110592
    float* yacc  = dts  + 110592;             //             884736
    float* Hsum  = yacc + 884736;             // 8*CH*4*DE*4 = 2359296
    float* carry = Hsum + 2359296;            //             2359296
    float* dlsum = carry + 2359296;           // 8*CH*DE  =  147456
    // total 9,105,408 floats = 36.4 MB

    k_inproj<<<B_ * L_, 2 * DE, 0, stream>>>(x, wip, xh, zb);
    k_conv<<<(B_ * L_ * DE + 255) / 256, 256, 0, stream>>>(xh, cw, cb, xc);
    k_proj<<<B_ * K_ * (L_ / JT_), 256, 0, stream>>>(xc, xpw, BsT, CsT, dts);
    hipMemsetAsync(yacc, 0, 884736 * sizeof(float), stream);
    k_scan1<<<B_ * K_ * CH_, DE, 0, stream>>>(xc, BsT, dts, dtw, dtb, alog, Hsum, dlsum);
    k_comb<<<(B_ * K_ * 4 * DE) / 256, 256, 0, stream>>>(Hsum, dlsum, alog, carry);
    k_scan2<<<B_ * K_ * CH_, DE, 0, stream>>>(xc, BsT, CsT, dts, dtw, dtb, alog, Ds, carry, yacc);
    k_out<<<B_ * L_, DE, 0, stream>>>(yacc, zb, gam, bet, opw, out);
}

// Round 4
// 245.698 us; speedup vs baseline: 5.9680x; 1.4920x over previous
//
#include <hip/hip_runtime.h>
#include <cmath>

// Problem constants (from reference)
#define B_  2
#define H_  48
#define W_  48
#define DM  96
#define DE  192
#define K_  4
#define N_  16
#define R_  6
#define L_  (H_ * W_)          // 2304
#define CC  (R_ + 2 * N_)      // 38
#define CH_ 96                 // chunks per (b,k) chain-group
#define LC_ (L_ / CH_)         // 24 steps per chunk
#define JT_ 16                 // j-tile in k_proj
#define JT1 16                 // l-tile in k_inproj
#define JT5 4                  // l-tile in k_out

__device__ __forceinline__ float silu_f(float x) { return x / (1.f + __expf(-x)); }
__device__ __forceinline__ float softplus_f(float x) {
    return x > 20.f ? x : log1pf(__expf(x));
}

// scan-position j -> original row-major spatial index, per direction k.
__device__ __forceinline__ int perm_idx(int k, int j) {
    if (k == 0) return j;
    if (k == 1) return L_ - 1 - j;
    if (k == 2) return (j % H_) * W_ + (j / H_);
    int m = L_ - 1 - j;
    return (m % H_) * W_ + (m / H_);
}

// ---------------------------------------------------------------------------
// K0: weight transposes (tiny; runs every call).
//     wipT[c*384+d] = wip[d*96+c]   (96 x 384)
//     opwT[d*96+c]  = opw[c*192+d]  (192 x 96)
// ---------------------------------------------------------------------------
__global__ __launch_bounds__(256) void
k_prep(const float* __restrict__ wip, const float* __restrict__ opw,
       float* __restrict__ wipT, float* __restrict__ opwT) {
    int t = blockIdx.x * 256 + threadIdx.x;
    if (t < DM * 2 * DE) {                       // 36864
        int c = t / (2 * DE), d = t % (2 * DE);
        wipT[t] = wip[d * DM + c];
    } else if (t < DM * 2 * DE + DE * DM) {      // + 18432
        int i = t - DM * 2 * DE;
        int d = i / DM, c = i % DM;
        opwT[i] = opw[c * DE + d];
    }
}

// ---------------------------------------------------------------------------
// K1: xz = x @ in_proj_w^T ; split -> xh (B,L,DE), z = silu (B,L,DE)
//     16 positions per block; thread = output channel; coalesced wipT reads,
//     each weight load feeds 16 FMAs.
// ---------------------------------------------------------------------------
__global__ __launch_bounds__(2 * DE) void
k_inproj(const float* __restrict__ x, const float* __restrict__ wT,
         float* __restrict__ xh, float* __restrict__ zb) {
    int tile = blockIdx.x;          // 0 .. B*L/JT1-1
    int t    = threadIdx.x;         // 0..383 = output channel
    int bl0  = tile * JT1;
    __shared__ __align__(16) float xr[JT1][DM];
    for (int i = t; i < JT1 * DM; i += 2 * DE)
        xr[i / DM][i % DM] = x[(size_t)bl0 * DM + i];
    __syncthreads();

    float acc[JT1];
#pragma unroll
    for (int j = 0; j < JT1; ++j) acc[j] = 0.f;
#pragma unroll 4
    for (int c = 0; c < DM; ++c) {
        float wv = wT[c * (2 * DE) + t];
#pragma unroll
        for (int j = 0; j < JT1; ++j) acc[j] += xr[j][c] * wv;
    }
    if (t < DE) {
#pragma unroll
        for (int j = 0; j < JT1; ++j)
            xh[(size_t)(bl0 + j) * DE + t] = acc[j];
    } else {
        int d = t - DE;
#pragma unroll
        for (int j = 0; j < JT1; ++j)
            zb[(size_t)(bl0 + j) * DE + d] = silu_f(acc[j]);
    }
}

// ---------------------------------------------------------------------------
// K2: depthwise 3x3 SAME conv + bias + silu.  xh (B,L,DE) -> xc (B,L,DE)
// ---------------------------------------------------------------------------
__global__ void k_conv(const float* __restrict__ xh, const float* __restrict__ cw,
                       const float* __restrict__ cb, float* __restrict__ xc) {
    int t = blockIdx.x * blockDim.x + threadIdx.x;
    if (t >= B_ * L_ * DE) return;
    int d = t % DE;
    int l = (t / DE) % L_;
    int b = t / (DE * L_);
    int h = l / W_, w = l % W_;
    float acc = cb[d];
#pragma unroll
    for (int i = 0; i < 3; ++i) {
        int hh = h + i - 1;
        if (hh < 0 || hh >= H_) continue;
#pragma unroll
        for (int j = 0; j < 3; ++j) {
            int ww = w + j - 1;
            if (ww < 0 || ww >= W_) continue;
            acc += xh[((b * L_) + hh * W_ + ww) * DE + d] * cw[d * 9 + i * 3 + j];
        }
    }
    xc[t] = silu_f(acc);
}

// ---------------------------------------------------------------------------
// K3: j-tiled projection. Block = (bk, tile of 16 j). Weight staged into LDS
//     TRANSPOSED (wl[d][c], c padded to 40) so compute reads are ~2-way max.
// ---------------------------------------------------------------------------
__global__ __launch_bounds__(256) void
k_proj(const float* __restrict__ xc, const float* __restrict__ xpw,
       float* __restrict__ BsT, float* __restrict__ CsT, float* __restrict__ dts) {
    int blk = blockIdx.x;                // bk * (L/JT) + tile
    int jt  = blk % (L_ / JT_);
    int bk  = blk / (L_ / JT_);
    int k   = bk % K_;
    int b   = bk / K_;
    int j0  = jt * JT_;
    int t   = threadIdx.x;

    __shared__ __align__(16) float xv[JT_][DE];   // 12 KB
    __shared__ float wl[DE][40];                  // 30.7 KB (pad 38->40)
    for (int idx = t; idx < JT_ * DE; idx += 256) {
        int jj = idx / DE, dd = idx % DE;
        int p  = perm_idx(k, j0 + jj);
        xv[jj][dd] = xc[((size_t)b * L_ + p) * DE + dd];
    }
    for (int idx = t; idx < CC * DE; idx += 256) {
        int c = idx / DE, dd = idx % DE;
        wl[dd][c] = xpw[((size_t)k * CC + c) * DE + dd];
    }
    __syncthreads();

    for (int o = t; o < JT_ * 40; o += 256) {
        int jj = o / 40, c = o % 40;
        if (c >= CC) continue;
        float acc = 0.f;
#pragma unroll 8
        for (int dd = 0; dd < DE; ++dd) acc += xv[jj][dd] * wl[dd][c];
        int j = j0 + jj;
        if (c < R_)            dts[((size_t)bk * L_ + j) * R_ + c] = acc;
        else if (c < R_ + N_)  BsT[((size_t)bk * L_ + j) * N_ + (c - R_)] = acc;
        else                   CsT[((size_t)bk * L_ + j) * N_ + (c - R_ - N_)] = acc;
    }
}

// ---------------------------------------------------------------------------
// K4a: chunk-local scan. Block = (bk, chunk); thread = channel d, all 16
//      n-states in registers. Emits h_end and sum-of-delta per chunk.
// ---------------------------------------------------------------------------
__global__ __launch_bounds__(DE) void
k_scan1(const float* __restrict__ xc, const float* __restrict__ BsT,
        const float* __restrict__ dts, const float* __restrict__ dtw,
        const float* __restrict__ dtb, const float* __restrict__ A_logs,
        float* __restrict__ Hsum, float* __restrict__ dlsum_g) {
    int blk = blockIdx.x;            // bk*CH_ + c
    int c   = blk % CH_;
    int bk  = blk / CH_;
    int k   = bk % K_;
    int b   = bk / K_;
    int d   = threadIdx.x;           // 0..191
    int j0  = c * LC_;

    __shared__ __align__(16) float Bl[LC_ * N_];
    __shared__ __align__(16) float Tl[LC_ * R_];
    for (int idx = d; idx < LC_ * N_; idx += DE)
        Bl[idx] = BsT[((size_t)bk * L_ + j0) * N_ + idx];
    for (int idx = d; idx < LC_ * R_; idx += DE)
        Tl[idx] = dts[((size_t)bk * L_ + j0) * R_ + idx];
    __syncthreads();

    float An[N_];
    {
        const float4* Ap = (const float4*)(A_logs + ((size_t)k * DE + d) * N_);
#pragma unroll
        for (int q = 0; q < 4; ++q) {
            float4 a = Ap[q];
            An[4*q+0] = -__expf(a.x); An[4*q+1] = -__expf(a.y);
            An[4*q+2] = -__expf(a.z); An[4*q+3] = -__expf(a.w);
        }
    }
    float wdt[R_];
#pragma unroll
    for (int r = 0; r < R_; ++r) wdt[r] = dtw[((size_t)k * DE + d) * R_ + r];
    float bias = dtb[k * DE + d];

    float h[N_];
#pragma unroll
    for (int n = 0; n < N_; ++n) h[n] = 0.f;
    float dlsum = 0.f;

    const float* up = xc + (size_t)b * L_ * DE + d;
#pragma unroll 4
    for (int jj = 0; jj < LC_; ++jj) {
        int j = j0 + jj;
        int p = perm_idx(k, j);
        float u  = up[(size_t)p * DE];
        float dt = bias;
#pragma unroll
        for (int r = 0; r < R_; ++r) dt += Tl[jj * R_ + r] * wdt[r];
        float dl = softplus_f(dt);
        dlsum += dl;
        float du = dl * u;
        const float4* B4 = (const float4*)(Bl + jj * N_);
#pragma unroll
        for (int q = 0; q < 4; ++q) {
            float4 bq = B4[q];
            h[4*q+0] = __expf(dl * An[4*q+0]) * h[4*q+0] + du * bq.x;
            h[4*q+1] = __expf(dl * An[4*q+1]) * h[4*q+1] + du * bq.y;
            h[4*q+2] = __expf(dl * An[4*q+2]) * h[4*q+2] + du * bq.z;
            h[4*q+3] = __expf(dl * An[4*q+3]) * h[4*q+3] + du * bq.w;
        }
    }
    float4* Hp = (float4*)Hsum;
#pragma unroll
    for (int q = 0; q < 4; ++q)
        Hp[((size_t)blk * 4 + q) * DE + d] =
            make_float4(h[4*q], h[4*q+1], h[4*q+2], h[4*q+3]);
    dlsum_g[(size_t)blk * DE + d] = dlsum;
}

// ---------------------------------------------------------------------------
// K4b: sequential combine of chunk summaries -> carry_in per chunk.
// ---------------------------------------------------------------------------
__global__ __launch_bounds__(256) void
k_comb(const float* __restrict__ Hsum, const float* __restrict__ dlsum_g,
       const float* __restrict__ A_logs, float* __restrict__ carry) {
    int tid = blockIdx.x * 256 + threadIdx.x;  // d fastest
    int d  = tid % DE;
    int q  = (tid / DE) % 4;
    int bk = tid / (DE * 4);
    int k  = bk % K_;
    float4 An;
    {
        const float4* Ap = (const float4*)(A_logs + ((size_t)k * DE + d) * N_);
        float4 a = Ap[q];
        An = make_float4(-__expf(a.x), -__expf(a.y), -__expf(a.z), -__expf(a.w));
    }
    const float4* Hp = (const float4*)Hsum;
    float4*       Cp = (float4*)carry;
    float4 cy = make_float4(0.f, 0.f, 0.f, 0.f);
#pragma unroll 4
    for (int c = 0; c < CH_; ++c) {
        size_t blk = (size_t)bk * CH_ + c;
        Cp[(blk * 4 + q) * DE + d] = cy;
        float  ds = dlsum_g[blk * DE + d];
        float4 H  = Hp[(blk * 4 + q) * DE + d];
        cy.x = __expf(ds * An.x) * cy.x + H.x;
        cy.y = __expf(ds * An.y) * cy.y + H.y;
        cy.z = __expf(ds * An.z) * cy.z + H.z;
        cy.w = __expf(ds * An.w) * cy.w + H.w;
    }
}

// ---------------------------------------------------------------------------
// K4c: rescan with carry, emit y via atomicAdd into yacc (B,L,DE).
// ---------------------------------------------------------------------------
__global__ __launch_bounds__(DE) void
k_scan2(const float* __restrict__ xc, const float* __restrict__ BsT,
        const float* __restrict__ CsT, const float* __restrict__ dts,
        const float* __restrict__ dtw, const float* __restrict__ dtb,
        const float* __restrict__ A_logs, const float* __restrict__ Ds,
        const float* __restrict__ carry, float* __restrict__ yacc) {
    int blk = blockIdx.x;
    int c   = blk % CH_;
    int bk  = blk / CH_;
    int k   = bk % K_;
    int b   = bk / K_;
    int d   = threadIdx.x;
    int j0  = c * LC_;

    __shared__ __align__(16) float Bl[LC_ * N_];
    __shared__ __align__(16) float Cl[LC_ * N_];
    __shared__ __align__(16) float Tl[LC_ * R_];
    for (int idx = d; idx < LC_ * N_; idx += DE) {
        Bl[idx] = BsT[((size_t)bk * L_ + j0) * N_ + idx];
        Cl[idx] = CsT[((size_t)bk * L_ + j0) * N_ + idx];
    }
    for (int idx = d; idx < LC_ * R_; idx += DE)
        Tl[idx] = dts[((size_t)bk * L_ + j0) * R_ + idx];
    __syncthreads();

    float An[N_];
    {
        const float4* Ap = (const float4*)(A_logs + ((size_t)k * DE + d) * N_);
#pragma unroll
        for (int q = 0; q < 4; ++q) {
            float4 a = Ap[q];
            An[4*q+0] = -__expf(a.x); An[4*q+1] = -__expf(a.y);
            An[4*q+2] = -__expf(a.z); An[4*q+3] = -__expf(a.w);
        }
    }
    float wdt[R_];
#pragma unroll
    for (int r = 0; r < R_; ++r) wdt[r] = dtw[((size_t)k * DE + d) * R_ + r];
    float bias = dtb[k * DE + d];
    float Dv   = Ds[k * DE + d];

    float h[N_];
    {
        const float4* Cp = (const float4*)carry;
#pragma unroll
        for (int q = 0; q < 4; ++q) {
            float4 cv = Cp[((size_t)blk * 4 + q) * DE + d];
            h[4*q+0] = cv.x; h[4*q+1] = cv.y; h[4*q+2] = cv.z; h[4*q+3] = cv.w;
        }
    }

    const float* up = xc + (size_t)b * L_ * DE + d;
    float*       yp = yacc + (size_t)b * L_ * DE + d;
#pragma unroll 2
    for (int jj = 0; jj < LC_; ++jj) {
        int j = j0 + jj;
        int p = perm_idx(k, j);
        float u  = up[(size_t)p * DE];
        float dt = bias;
#pragma unroll
        for (int r = 0; r < R_; ++r) dt += Tl[jj * R_ + r] * wdt[r];
        float dl = softplus_f(dt);
        float du = dl * u;
        float y  = Dv * u;
        const float4* B4 = (const float4*)(Bl + jj * N_);
        const float4* C4 = (const float4*)(Cl + jj * N_);
#pragma unroll
        for (int q = 0; q < 4; ++q) {
            float4 bq = B4[q], cq = C4[q];
            h[4*q+0] = __expf(dl * An[4*q+0]) * h[4*q+0] + du * bq.x;  y += h[4*q+0] * cq.x;
            h[4*q+1] = __expf(dl * An[4*q+1]) * h[4*q+1] + du * bq.y;  y += h[4*q+1] * cq.y;
            h[4*q+2] = __expf(dl * An[4*q+2]) * h[4*q+2] + du * bq.z;  y += h[4*q+2] * cq.z;
            h[4*q+3] = __expf(dl * An[4*q+3]) * h[4*q+3] + du * bq.w;  y += h[4*q+3] * cq.w;
        }
        atomicAdd(&yp[(size_t)p * DE], y);
    }
}

// ---------------------------------------------------------------------------
// K5: LayerNorm + *z + out-proj. 4 positions per block (768 threads).
//     Out-proj reads opwT coalesced; d-range split in two halves.
// ---------------------------------------------------------------------------
__global__ __launch_bounds__(JT5 * DE) void
k_out(const float* __restrict__ yacc, const float* __restrict__ zb,
      const float* __restrict__ gamma, const float* __restrict__ beta,
      const float* __restrict__ opwT, float* __restrict__ out) {
    int tile = blockIdx.x;           // 0 .. B*L/JT5-1
    int t  = threadIdx.x;            // 0..767
    int li = t / DE;                 // 0..3 position within tile
    int s  = t % DE;                 // 0..191 channel
    int bl = tile * JT5 + li;
    __shared__ __align__(16) float ylds[JT5][DE];
    __shared__ float red[JT5][4];
    __shared__ float part[JT5][DM];

    float v = yacc[(size_t)bl * DE + s];
    float sum = v;
    for (int off = 32; off; off >>= 1) sum += __shfl_xor(sum, off, 64);
    int wid = (t >> 6) % 3;          // wave within the 3-wave li group
    if ((t & 63) == 0) red[li][wid] = sum;
    __syncthreads();
    float mu = (red[li][0] + red[li][1] + red[li][2]) * (1.f / DE);
    float tv = v - mu;
    float s2 = tv * tv;
    for (int off = 32; off; off >>= 1) s2 += __shfl_xor(s2, off, 64);
    __syncthreads();
    if ((t & 63) == 0) red[li][wid] = s2;
    __syncthreads();
    float var = (red[li][0] + red[li][1] + red[li][2]) * (1.f / DE);

    float yn = tv * rsqrtf(var + 1e-5f) * gamma[s] + beta[s];
    ylds[li][s] = yn * zb[(size_t)bl * DE + s];
    __syncthreads();

    int half = s / DM;               // which 96-wide d range
    int c    = s % DM;               // output channel
    float acc = 0.f;
    const float* wp = opwT + (size_t)(half * DM) * DM;
#pragma unroll 8
    for (int dd = 0; dd < DM; ++dd)
        acc += ylds[li][half * DM + dd] * wp[dd * DM + c];
    if (half == 1) part[li][c] = acc;
    __syncthreads();
    if (half == 0) out[(size_t)bl * DM + c] = acc + part[li][c];
}

// ---------------------------------------------------------------------------
extern "C" void kernel_launch(void* const* d_in, const int* in_sizes, int n_in,
                              void* d_out, int out_size, void* d_ws, size_t ws_size,
                              hipStream_t stream) {
    const float* x    = (const float*)d_in[0];
    const float* wip  = (const float*)d_in[1];
    const float* cw   = (const float*)d_in[2];
    const float* cb   = (const float*)d_in[3];
    const float* xpw  = (const float*)d_in[4];
    const float* dtw  = (const float*)d_in[5];
    const float* dtb  = (const float*)d_in[6];
    const float* alog = (const float*)d_in[7];
    const float* Ds   = (const float*)d_in[8];
    const float* gam  = (const float*)d_in[9];
    const float* bet  = (const float*)d_in[10];
    const float* opw  = (const float*)d_in[11];
    float* out = (float*)d_out;

    float* ws    = (float*)d_ws;
    float* xh    = ws;                        // B*L*DE   =  884736
    float* zb    = xh   + 884736;             //             884736
    float* xc    = zb   + 884736;             //             884736
    float* BsT   = xc   + 884736;             // B*K*L*N  =  294912
    float* CsT   = BsT  + 294912;             //             294912
    float* dts   = CsT  + 294912;             // B*K*L*R  =  110592
    float* yacc  = dts  + 110592;             //             884736
    float* Hsum  = yacc + 884736;             // 8*CH*4*DE*4 = 2359296
    float* carry = Hsum + 2359296;            //             2359296
    float* dlsum = carry + 2359296;           // 8*CH*DE  =  147456
    float* wipT  = dlsum + 147456;            // 96*384   =   36864
    float* opwT  = wipT + 36864;              // 192*96   =   18432
    // total ~36.7 MB of d_ws

    k_prep<<<(DM * 2 * DE + DE * DM + 255) / 256, 256, 0, stream>>>(wip, opw, wipT, opwT);
    k_inproj<<<B_ * L_ / JT1, 2 * DE, 0, stream>>>(x, wipT, xh, zb);
    k_conv<<<(B_ * L_ * DE + 255) / 256, 256, 0, stream>>>(xh, cw, cb, xc);
    k_proj<<<B_ * K_ * (L_ / JT_), 256, 0, stream>>>(xc, xpw, BsT, CsT, dts);
    hipMemsetAsync(yacc, 0, 884736 * sizeof(float), stream);
    k_scan1<<<B_ * K_ * CH_, DE, 0, stream>>>(xc, BsT, dts, dtw, dtb, alog, Hsum, dlsum);
    k_comb<<<(B_ * K_ * 4 * DE) / 256, 256, 0, stream>>>(Hsum, dlsum, alog, carry);
    k_scan2<<<B_ * K_ * CH_, DE, 0, stream>>>(xc, BsT, CsT, dts, dtw, dtb, alog, Ds, carry, yacc);
    k_out<<<B_ * L_ / JT5, JT5 * DE, 0, stream>>>(yacc, zb, gam, bet, opwT, out);
}